// Round 1
// baseline (2132.529 us; speedup 1.0000x reference)
//
#include <hip/hip_runtime.h>
#include <hip/hip_bf16.h>
#include <math.h>

// Problem constants (match reference setup_inputs)
static constexpr int Nn   = 50000;
static constexpr int Ee   = 1200000;
static constexpr int FIN  = 128;
static constexpr int HID  = 64;
static constexpr int NCLS = 40;

// ---------------------------------------------------------------------------
// deg[d] += 1 for each edge (unweighted in-degree)
__global__ __launch_bounds__(256) void deg_kernel(const int* __restrict__ dst,
                                                  float* __restrict__ deg) {
    int e = blockIdx.x * 256 + threadIdx.x;
    if (e < Ee) atomicAdd(&deg[dst[e]], 1.0f);
}

// ---------------------------------------------------------------------------
// Fused dual GEMM: yl = x @ Wl ; z = x @ Wr + b   (x: [n,K], W: [K,64])
// Block: 256 threads -> 32 rows x 128 output cols (64 for yl, 64 for z).
// K tiled by 64; W tiles + x tile staged in LDS (~40 KB).
template <int K>
__global__ __launch_bounds__(256) void gemm2_kernel(
    const float* __restrict__ x, const float* __restrict__ Wl,
    const float* __restrict__ Wr, const float* __restrict__ b,
    float* __restrict__ yl, float* __restrict__ z, int n) {
    __shared__ float w_s[2][64 * 64];  // 32 KB
    __shared__ float x_s[32][64];      // 8 KB
    const int col  = threadIdx.x & 63;
    const int half = (threadIdx.x >> 6) & 1;  // 0 -> yl, 1 -> z
    const int rowo = threadIdx.x >> 7;        // 0..1
    const int row0 = blockIdx.x * 32;

    float acc[16];
#pragma unroll
    for (int i = 0; i < 16; ++i) acc[i] = 0.f;

    for (int kt = 0; kt < K; kt += 64) {
        __syncthreads();
        for (int i = threadIdx.x; i < 64 * 64; i += 256) {
            w_s[0][i] = Wl[(kt + (i >> 6)) * 64 + (i & 63)];
            w_s[1][i] = Wr[(kt + (i >> 6)) * 64 + (i & 63)];
        }
        for (int i = threadIdx.x; i < 32 * 64; i += 256) {
            int r = row0 + (i >> 6);
            x_s[i >> 6][i & 63] = (r < n) ? x[r * K + kt + (i & 63)] : 0.f;
        }
        __syncthreads();
#pragma unroll
        for (int rr = 0; rr < 16; ++rr) {
            const int lr = rowo + 2 * rr;
            float a = 0.f;
#pragma unroll
            for (int k = 0; k < 64; ++k)
                a += x_s[lr][k] * w_s[half][k * 64 + col];
            acc[rr] += a;
        }
    }

    const float bias = b[col];
    float* __restrict__ outp = half ? z : yl;
#pragma unroll
    for (int rr = 0; rr < 16; ++rr) {
        int row = row0 + rowo + 2 * rr;
        if (row < n) outp[row * 64 + col] = acc[rr] + (half ? bias : 0.f);
    }
}

// ---------------------------------------------------------------------------
// Edge-parallel scatter: summ[dst] += yl[src] * w.  One wave = one edge,
// lane = feature (64 features -> full wave, coalesced 256B per edge).
__global__ __launch_bounds__(256) void scatter_kernel(
    const int* __restrict__ src, const int* __restrict__ dst,
    const float* __restrict__ ew, const float* __restrict__ yl,
    float* __restrict__ summ) {
    int idx = blockIdx.x * 256 + threadIdx.x;
    int e = idx >> 6;
    int f = idx & 63;
    if (e < Ee) {
        int s = src[e];
        int d = dst[e];
        float w = ew[e];
        atomicAdd(&summ[d * 64 + f], yl[s * 64 + f] * w);
    }
}

// ---------------------------------------------------------------------------
// x_out = relu(summ / max(deg,1) + z)
__global__ __launch_bounds__(256) void finish_kernel(
    const float* __restrict__ summ, const float* __restrict__ z,
    const float* __restrict__ deg, float* __restrict__ xout, int n) {
    int idx = blockIdx.x * 256 + threadIdx.x;
    if (idx < n * 64) {
        int i = idx >> 6;
        float v = summ[idx] / fmaxf(deg[i], 1.0f) + z[idx];
        xout[idx] = fmaxf(v, 0.0f);
    }
}

// ---------------------------------------------------------------------------
// logits = [x1|x2|x3] @ Wlin + blin; out = log_softmax(logits)
// One wave per row; lanes 0..39 compute one class each.
__global__ __launch_bounds__(256) void final_kernel(
    const float* __restrict__ x1, const float* __restrict__ x2,
    const float* __restrict__ x3, const float* __restrict__ Wlin,
    const float* __restrict__ blin, float* __restrict__ out, int n) {
    int row  = (blockIdx.x * 256 + threadIdx.x) >> 6;
    int lane = threadIdx.x & 63;
    if (row >= n) return;

    float acc = 0.f;
    if (lane < NCLS) {
        acc = blin[lane];
        const float* xr = x1 + row * 64;
#pragma unroll
        for (int k = 0; k < 64; ++k) acc += xr[k] * Wlin[k * NCLS + lane];
        xr = x2 + row * 64;
#pragma unroll
        for (int k = 0; k < 64; ++k) acc += xr[k] * Wlin[(64 + k) * NCLS + lane];
        xr = x3 + row * 64;
#pragma unroll
        for (int k = 0; k < 64; ++k) acc += xr[k] * Wlin[(128 + k) * NCLS + lane];
    }

    float lg = (lane < NCLS) ? acc : -INFINITY;
    float m = lg;
#pragma unroll
    for (int off = 32; off; off >>= 1) m = fmaxf(m, __shfl_xor(m, off));
    float ex = (lane < NCLS) ? expf(lg - m) : 0.f;
    float s = ex;
#pragma unroll
    for (int off = 32; off; off >>= 1) s += __shfl_xor(s, off);
    if (lane < NCLS) out[row * NCLS + lane] = lg - m - logf(s);
}

// ---------------------------------------------------------------------------
extern "C" void kernel_launch(void* const* d_in, const int* in_sizes, int n_in,
                              void* d_out, int out_size, void* d_ws, size_t ws_size,
                              hipStream_t stream) {
    const float* x0  = (const float*)d_in[0];
    const int*   ei  = (const int*)d_in[1];
    const float* ew  = (const float*)d_in[2];
    const float* W1l = (const float*)d_in[3];
    const float* W1r = (const float*)d_in[4];
    const float* b1  = (const float*)d_in[5];
    const float* W2l = (const float*)d_in[6];
    const float* W2r = (const float*)d_in[7];
    const float* b2  = (const float*)d_in[8];
    const float* W3l = (const float*)d_in[9];
    const float* W3r = (const float*)d_in[10];
    const float* b3  = (const float*)d_in[11];
    const float* Wlin = (const float*)d_in[12];
    const float* blin = (const float*)d_in[13];
    float* out = (float*)d_out;

    const int* src = ei;       // edge_index[0]
    const int* dst = ei + Ee;  // edge_index[1]

    // Workspace layout (floats)
    const size_t N64 = (size_t)Nn * 64;
    float* ws   = (float*)d_ws;
    float* deg  = ws;                  // Nn (padded to 50176)
    float* yl   = ws + 50176;          // N64
    float* z    = yl + N64;            // N64
    float* summ = z + N64;             // N64
    float* x1   = summ + N64;          // N64
    float* x2   = x1 + N64;            // N64
    float* x3   = x2 + N64;            // N64

    const int gemm_blocks    = (Nn + 31) / 32;
    const int scatter_blocks = (Ee * 64) / 256;  // exact multiple
    const int finish_blocks  = (Nn * 64 + 255) / 256;
    const int final_blocks   = (Nn + 3) / 4;

    // degree (once)
    hipMemsetAsync(deg, 0, Nn * sizeof(float), stream);
    deg_kernel<<<(Ee + 255) / 256, 256, 0, stream>>>(dst, deg);

    // ---- layer 1 (K = 128) ----
    gemm2_kernel<FIN><<<gemm_blocks, 256, 0, stream>>>(x0, W1l, W1r, b1, yl, z, Nn);
    hipMemsetAsync(summ, 0, N64 * sizeof(float), stream);
    scatter_kernel<<<scatter_blocks, 256, 0, stream>>>(src, dst, ew, yl, summ);
    finish_kernel<<<finish_blocks, 256, 0, stream>>>(summ, z, deg, x1, Nn);

    // ---- layer 2 (K = 64) ----
    gemm2_kernel<HID><<<gemm_blocks, 256, 0, stream>>>(x1, W2l, W2r, b2, yl, z, Nn);
    hipMemsetAsync(summ, 0, N64 * sizeof(float), stream);
    scatter_kernel<<<scatter_blocks, 256, 0, stream>>>(src, dst, ew, yl, summ);
    finish_kernel<<<finish_blocks, 256, 0, stream>>>(summ, z, deg, x2, Nn);

    // ---- layer 3 (K = 64) ----
    gemm2_kernel<HID><<<gemm_blocks, 256, 0, stream>>>(x2, W3l, W3r, b3, yl, z, Nn);
    hipMemsetAsync(summ, 0, N64 * sizeof(float), stream);
    scatter_kernel<<<scatter_blocks, 256, 0, stream>>>(src, dst, ew, yl, summ);
    finish_kernel<<<finish_blocks, 256, 0, stream>>>(summ, z, deg, x3, Nn);

    // ---- final linear + log_softmax ----
    final_kernel<<<final_blocks, 256, 0, stream>>>(x1, x2, x3, Wlin, blin, out, Nn);
}

// Round 2
// 707.238 us; speedup vs baseline: 3.0153x; 3.0153x over previous
//
#include <hip/hip_runtime.h>
#include <hip/hip_bf16.h>
#include <math.h>

// Problem constants (match reference setup_inputs)
static constexpr int Nn   = 50000;
static constexpr int Ee   = 1200000;
static constexpr int FIN  = 128;
static constexpr int HID  = 64;
static constexpr int NCLS = 40;

// ---------------------------------------------------------------------------
// CSR build step 1: count in-degree (int)
__global__ __launch_bounds__(256) void count_kernel(const int* __restrict__ dst,
                                                    int* __restrict__ cnt) {
    int e = blockIdx.x * 256 + threadIdx.x;
    if (e < Ee) atomicAdd(&cnt[dst[e]], 1);
}

// CSR build step 2: exclusive prefix sum over cnt -> rowptr (and cursor copy).
// Single block of 1024 threads, Hillis-Steele scan per 1024-chunk.
__global__ __launch_bounds__(1024) void scan_kernel(const int* __restrict__ cnt,
                                                    int* __restrict__ rowptr,
                                                    int* __restrict__ cursor) {
    __shared__ int sdata[1024];
    int running = 0;
    for (int base = 0; base < Nn; base += 1024) {
        int i = base + threadIdx.x;
        int v = (i < Nn) ? cnt[i] : 0;
        sdata[threadIdx.x] = v;
        __syncthreads();
        for (int off = 1; off < 1024; off <<= 1) {
            int t = (threadIdx.x >= off) ? sdata[threadIdx.x - off] : 0;
            __syncthreads();
            sdata[threadIdx.x] += t;
            __syncthreads();
        }
        int incl = sdata[threadIdx.x];
        if (i < Nn) {
            rowptr[i] = running + incl - v;
            cursor[i] = running + incl - v;
        }
        running += sdata[1023];
        __syncthreads();
    }
    if (threadIdx.x == 0) rowptr[Nn] = running;
}

// CSR build step 3: scatter edges into slots
__global__ __launch_bounds__(256) void fill_kernel(
    const int* __restrict__ src, const int* __restrict__ dst,
    const float* __restrict__ ew, int* __restrict__ cursor,
    int* __restrict__ colA, float* __restrict__ wtA) {
    int e = blockIdx.x * 256 + threadIdx.x;
    if (e < Ee) {
        int d = dst[e];
        int p = atomicAdd(&cursor[d], 1);
        colA[p] = src[e];
        wtA[p]  = ew[e];
    }
}

// ---------------------------------------------------------------------------
// Fused dual GEMM: yl = x @ Wl ; z = x @ Wr + b   (x: [n,K], W: [K,64])
// 16 rows/block, 256 threads. Thread: col=tid&63, half=(tid>>6)&1 selects
// Wl vs Wr, rh=tid>>7 selects rows rh*8..rh*8+7 -> acc[8]. W tile (64x64 x2)
// + x rows staged in LDS. k-loop kept rolled to avoid register spills
// (R1 post-mortem: full unroll -> 256 VGPR + 862MB scratch traffic).
template <int K>
__global__ __launch_bounds__(256, 4) void gemm2_kernel(
    const float* __restrict__ x, const float* __restrict__ Wl,
    const float* __restrict__ Wr, const float* __restrict__ b,
    float* __restrict__ yl, float* __restrict__ z) {
    __shared__ float w_s[2][64 * 64];  // 32 KB
    __shared__ float x_s[16][K];       // 8 KB (K=128) / 4 KB (K=64)
    const int col  = threadIdx.x & 63;
    const int half = (threadIdx.x >> 6) & 1;  // 0 -> yl, 1 -> z
    const int rh   = threadIdx.x >> 7;        // 0..1
    const int row0 = blockIdx.x * 16;

    // stage x rows once (16 x K)
    for (int i = threadIdx.x; i < 16 * K; i += 256) {
        int r = i / K, c = i % K;
        x_s[r][c] = x[(row0 + r) * K + c];
    }

    float acc[8];
#pragma unroll
    for (int i = 0; i < 8; ++i) acc[i] = 0.f;

    for (int kt = 0; kt < K; kt += 64) {
        __syncthreads();
        for (int i = threadIdx.x; i < 64 * 64; i += 256) {
            int kr = i >> 6, kc = i & 63;
            w_s[0][i] = Wl[(kt + kr) * 64 + kc];
            w_s[1][i] = Wr[(kt + kr) * 64 + kc];
        }
        __syncthreads();
#pragma unroll 2
        for (int k4 = 0; k4 < 64; k4 += 4) {
            float w0 = w_s[half][(k4 + 0) * 64 + col];
            float w1 = w_s[half][(k4 + 1) * 64 + col];
            float w2 = w_s[half][(k4 + 2) * 64 + col];
            float w3 = w_s[half][(k4 + 3) * 64 + col];
#pragma unroll
            for (int r = 0; r < 8; ++r) {
                const float4 xv = *(const float4*)&x_s[rh * 8 + r][kt + k4];
                acc[r] += xv.x * w0 + xv.y * w1 + xv.z * w2 + xv.w * w3;
            }
        }
    }

    const float bias = b[col];
    float* __restrict__ outp = half ? z : yl;
#pragma unroll
    for (int r = 0; r < 8; ++r) {
        int row = row0 + rh * 8 + r;
        outp[row * 64 + col] = acc[r] + (half ? bias : 0.f);
    }
}

// ---------------------------------------------------------------------------
// Pull-mode aggregation + finish, fused: one wave per dst row, lane = feature.
// x_out = relu( (sum_{e in row} yl[col[e]] * wt[e]) / max(deg,1) + z[row] )
__global__ __launch_bounds__(256) void gather_kernel(
    const int* __restrict__ rowptr, const int* __restrict__ colA,
    const float* __restrict__ wtA, const float* __restrict__ yl,
    const float* __restrict__ z, float* __restrict__ xout) {
    int row  = (blockIdx.x * 256 + threadIdx.x) >> 6;
    int lane = threadIdx.x & 63;
    int beg = rowptr[row], end = rowptr[row + 1];
    float acc = 0.f;
    int e = beg;
    for (; e + 4 <= end; e += 4) {
        int   s0 = colA[e],   s1 = colA[e + 1],   s2 = colA[e + 2],   s3 = colA[e + 3];
        float w0 = wtA[e],    w1 = wtA[e + 1],    w2 = wtA[e + 2],    w3 = wtA[e + 3];
        float v0 = yl[s0 * 64 + lane], v1 = yl[s1 * 64 + lane];
        float v2 = yl[s2 * 64 + lane], v3 = yl[s3 * 64 + lane];
        acc += v0 * w0; acc += v1 * w1; acc += v2 * w2; acc += v3 * w3;
    }
    for (; e < end; ++e) acc += yl[colA[e] * 64 + lane] * wtA[e];
    float deg = (float)(end - beg);
    float v = acc / fmaxf(deg, 1.f) + z[row * 64 + lane];
    xout[row * 64 + lane] = fmaxf(v, 0.f);
}

// ---------------------------------------------------------------------------
// logits = [x1|x2|x3] @ Wlin + blin; out = log_softmax(logits)
// One wave per row; lanes 0..39 compute one class each.
__global__ __launch_bounds__(256) void final_kernel(
    const float* __restrict__ x1, const float* __restrict__ x2,
    const float* __restrict__ x3, const float* __restrict__ Wlin,
    const float* __restrict__ blin, float* __restrict__ out) {
    int row  = (blockIdx.x * 256 + threadIdx.x) >> 6;
    int lane = threadIdx.x & 63;

    float acc = 0.f;
    if (lane < NCLS) {
        acc = blin[lane];
        const float* xr = x1 + row * 64;
#pragma unroll
        for (int k = 0; k < 64; ++k) acc += xr[k] * Wlin[k * NCLS + lane];
        xr = x2 + row * 64;
#pragma unroll
        for (int k = 0; k < 64; ++k) acc += xr[k] * Wlin[(64 + k) * NCLS + lane];
        xr = x3 + row * 64;
#pragma unroll
        for (int k = 0; k < 64; ++k) acc += xr[k] * Wlin[(128 + k) * NCLS + lane];
    }

    float lg = (lane < NCLS) ? acc : -INFINITY;
    float m = lg;
#pragma unroll
    for (int off = 32; off; off >>= 1) m = fmaxf(m, __shfl_xor(m, off));
    float ex = (lane < NCLS) ? expf(lg - m) : 0.f;
    float s = ex;
#pragma unroll
    for (int off = 32; off; off >>= 1) s += __shfl_xor(s, off);
    if (lane < NCLS) out[row * NCLS + lane] = lg - m - logf(s);
}

// ---------------------------------------------------------------------------
extern "C" void kernel_launch(void* const* d_in, const int* in_sizes, int n_in,
                              void* d_out, int out_size, void* d_ws, size_t ws_size,
                              hipStream_t stream) {
    const float* x0  = (const float*)d_in[0];
    const int*   ei  = (const int*)d_in[1];
    const float* ew  = (const float*)d_in[2];
    const float* W1l = (const float*)d_in[3];
    const float* W1r = (const float*)d_in[4];
    const float* b1  = (const float*)d_in[5];
    const float* W2l = (const float*)d_in[6];
    const float* W2r = (const float*)d_in[7];
    const float* b2  = (const float*)d_in[8];
    const float* W3l = (const float*)d_in[9];
    const float* W3r = (const float*)d_in[10];
    const float* b3  = (const float*)d_in[11];
    const float* Wlin = (const float*)d_in[12];
    const float* blin = (const float*)d_in[13];
    float* out = (float*)d_out;

    const int* src = ei;       // edge_index[0]
    const int* dst = ei + Ee;  // edge_index[1]

    // Workspace layout (4-byte elements)
    const size_t N64 = (size_t)Nn * 64;
    char* ws = (char*)d_ws;
    int*   cnt    = (int*)ws;                       // 50048
    int*   rowptr = cnt + 50048;                    // 50048 (Nn+1 used)
    int*   cursor = rowptr + 50048;                 // 50048
    int*   colA   = cursor + 50048;                 // Ee
    float* wtA    = (float*)(colA + Ee);            // Ee
    float* yl     = wtA + Ee;                       // N64
    float* zb     = yl + N64;                       // N64
    float* x1     = zb + N64;                       // N64
    float* x2     = x1 + N64;                       // N64
    float* x3     = x2 + N64;                       // N64

    const int eblocks      = (Ee + 255) / 256;
    const int gemm_blocks  = Nn / 16;   // 50000 = 16 * 3125, exact
    const int row_blocks   = Nn / 4;    // 4 waves (rows) per block, exact

    // ---- CSR build (per call; ws is re-poisoned) ----
    hipMemsetAsync(cnt, 0, Nn * sizeof(int), stream);
    count_kernel<<<eblocks, 256, 0, stream>>>(dst, cnt);
    scan_kernel<<<1, 1024, 0, stream>>>(cnt, rowptr, cursor);
    fill_kernel<<<eblocks, 256, 0, stream>>>(src, dst, ew, cursor, colA, wtA);

    // ---- layer 1 (K = 128) ----
    gemm2_kernel<FIN><<<gemm_blocks, 256, 0, stream>>>(x0, W1l, W1r, b1, yl, zb);
    gather_kernel<<<row_blocks, 256, 0, stream>>>(rowptr, colA, wtA, yl, zb, x1);

    // ---- layer 2 (K = 64) ----
    gemm2_kernel<HID><<<gemm_blocks, 256, 0, stream>>>(x1, W2l, W2r, b2, yl, zb);
    gather_kernel<<<row_blocks, 256, 0, stream>>>(rowptr, colA, wtA, yl, zb, x2);

    // ---- layer 3 (K = 64) ----
    gemm2_kernel<HID><<<gemm_blocks, 256, 0, stream>>>(x2, W3l, W3r, b3, yl, zb);
    gather_kernel<<<row_blocks, 256, 0, stream>>>(rowptr, colA, wtA, yl, zb, x3);

    // ---- final linear + log_softmax ----
    final_kernel<<<row_blocks, 256, 0, stream>>>(x1, x2, x3, Wlin, blin, out);
}

// Round 3
// 641.168 us; speedup vs baseline: 3.3260x; 1.1030x over previous
//
#include <hip/hip_runtime.h>
#include <hip/hip_bf16.h>
#include <math.h>

// Problem constants (match reference setup_inputs)
static constexpr int Nn   = 50000;
static constexpr int Ee   = 1200000;
static constexpr int FIN  = 128;
static constexpr int HID  = 64;
static constexpr int NCLS = 40;

typedef float f32x4  __attribute__((ext_vector_type(4)));
typedef short short8 __attribute__((ext_vector_type(8)));

__device__ inline unsigned short f2b(float f) {  // fp32 -> bf16 (RNE)
    unsigned int u = __builtin_bit_cast(unsigned int, f);
    return (unsigned short)((u + 0x7FFFu + ((u >> 16) & 1u)) >> 16);
}

// ---------------------------------------------------------------------------
// CSR build step 1: count in-degree (int)
__global__ __launch_bounds__(256) void count_kernel(const int* __restrict__ dst,
                                                    int* __restrict__ cnt) {
    int e = blockIdx.x * 256 + threadIdx.x;
    if (e < Ee) atomicAdd(&cnt[dst[e]], 1);
}

// CSR build step 2: exclusive prefix sum. 1024 threads, 49 elems/thread
// sequential + one 1024-wide LDS scan (R2 post-mortem: 49x Hillis-Steele
// passes were ~490 barrier rounds on one CU).
__global__ __launch_bounds__(1024) void scan_kernel(const int* __restrict__ cnt,
                                                    int* __restrict__ rowptr,
                                                    int* __restrict__ cursor) {
    __shared__ int sdata[1024];
    const int t = threadIdx.x;
    const int base = t * 49;
    int s = 0;
    for (int j = 0; j < 49; ++j) {
        int i = base + j;
        if (i < Nn) s += cnt[i];
    }
    sdata[t] = s;
    __syncthreads();
    for (int off = 1; off < 1024; off <<= 1) {
        int v = (t >= off) ? sdata[t - off] : 0;
        __syncthreads();
        sdata[t] += v;
        __syncthreads();
    }
    int run = sdata[t] - s;  // exclusive prefix of this chunk
    for (int j = 0; j < 49; ++j) {
        int i = base + j;
        if (i < Nn) {
            rowptr[i] = run;
            cursor[i] = run;
            run += cnt[i];
        }
    }
    if (t == 1023) rowptr[Nn] = run;  // total = Ee
}

// CSR build step 3: scatter edges into slots
__global__ __launch_bounds__(256) void fill_kernel(
    const int* __restrict__ src, const int* __restrict__ dst,
    const float* __restrict__ ew, int* __restrict__ cursor,
    int* __restrict__ colA, float* __restrict__ wtA) {
    int e = blockIdx.x * 256 + threadIdx.x;
    if (e < Ee) {
        int d = dst[e];
        int p = atomicAdd(&cursor[d], 1);
        colA[p] = src[e];
        wtA[p]  = ew[e];
    }
}

// ---------------------------------------------------------------------------
// Fused dual GEMM: yl = x @ Wl ; z = x @ Wr + b   (x: [n,K], W: [K,64])
// 16 rows/block, 256 threads. k-loop kept rolled to avoid register spills
// (R1 post-mortem: full unroll -> 256 VGPR + 862MB scratch traffic).
template <int K>
__global__ __launch_bounds__(256, 4) void gemm2_kernel(
    const float* __restrict__ x, const float* __restrict__ Wl,
    const float* __restrict__ Wr, const float* __restrict__ b,
    float* __restrict__ yl, float* __restrict__ z) {
    __shared__ float w_s[2][64 * 64];  // 32 KB
    __shared__ float x_s[16][K];
    const int col  = threadIdx.x & 63;
    const int half = (threadIdx.x >> 6) & 1;  // 0 -> yl, 1 -> z
    const int rh   = threadIdx.x >> 7;        // 0..1
    const int row0 = blockIdx.x * 16;

    for (int i = threadIdx.x; i < 16 * K; i += 256) {
        int r = i / K, c = i % K;
        x_s[r][c] = x[(row0 + r) * K + c];
    }

    float acc[8];
#pragma unroll
    for (int i = 0; i < 8; ++i) acc[i] = 0.f;

    for (int kt = 0; kt < K; kt += 64) {
        __syncthreads();
        for (int i = threadIdx.x; i < 64 * 64; i += 256) {
            int kr = i >> 6, kc = i & 63;
            w_s[0][i] = Wl[(kt + kr) * 64 + kc];
            w_s[1][i] = Wr[(kt + kr) * 64 + kc];
        }
        __syncthreads();
#pragma unroll 2
        for (int k4 = 0; k4 < 64; k4 += 4) {
            float w0 = w_s[half][(k4 + 0) * 64 + col];
            float w1 = w_s[half][(k4 + 1) * 64 + col];
            float w2 = w_s[half][(k4 + 2) * 64 + col];
            float w3 = w_s[half][(k4 + 3) * 64 + col];
#pragma unroll
            for (int r = 0; r < 8; ++r) {
                const float4 xv = *(const float4*)&x_s[rh * 8 + r][kt + k4];
                acc[r] += xv.x * w0 + xv.y * w1 + xv.z * w2 + xv.w * w3;
            }
        }
    }

    const float bias = b[col];
    float* __restrict__ outp = half ? z : yl;
#pragma unroll
    for (int r = 0; r < 8; ++r) {
        int row = row0 + rh * 8 + r;
        outp[row * 64 + col] = acc[r] + (half ? bias : 0.f);
    }
}

// ---------------------------------------------------------------------------
// Pull-mode aggregation + finish, fused: one wave per dst row, lane = feature.
__global__ __launch_bounds__(256) void gather_kernel(
    const int* __restrict__ rowptr, const int* __restrict__ colA,
    const float* __restrict__ wtA, const float* __restrict__ yl,
    const float* __restrict__ z, float* __restrict__ xout) {
    int row  = (blockIdx.x * 256 + threadIdx.x) >> 6;
    int lane = threadIdx.x & 63;
    int beg = rowptr[row], end = rowptr[row + 1];
    float acc = 0.f;
    int e = beg;
    for (; e + 4 <= end; e += 4) {
        int   s0 = colA[e],   s1 = colA[e + 1],   s2 = colA[e + 2],   s3 = colA[e + 3];
        float w0 = wtA[e],    w1 = wtA[e + 1],    w2 = wtA[e + 2],    w3 = wtA[e + 3];
        float v0 = yl[s0 * 64 + lane], v1 = yl[s1 * 64 + lane];
        float v2 = yl[s2 * 64 + lane], v3 = yl[s3 * 64 + lane];
        acc += v0 * w0; acc += v1 * w1; acc += v2 * w2; acc += v3 * w3;
    }
    for (; e < end; ++e) acc += yl[colA[e] * 64 + lane] * wtA[e];
    float deg = (float)(end - beg);
    float v = acc / fmaxf(deg, 1.f) + z[row * 64 + lane];
    xout[row * 64 + lane] = fmaxf(v, 0.f);
}

// ---------------------------------------------------------------------------
// Final: logits = [x1|x2|x3] @ Wlin + blin; out = log_softmax(logits).
// bf16 MFMA GEMM: block = 64 rows (4 waves x 16), N padded 40->48, K=192.
// A-layout: A[m=lane&15][k=(lane>>4)*8+j]; C/D: col=lane&15, row=quad*4+reg.
__global__ __launch_bounds__(256) void final_kernel(
    const float* __restrict__ x1, const float* __restrict__ x2,
    const float* __restrict__ x3, const float* __restrict__ Wlin,
    const float* __restrict__ blin, float* __restrict__ out) {
    __shared__ unsigned short xs[64 * 200];   // 64 rows x 192 (stride 200)
    __shared__ unsigned short wt[48 * 200];   // Wlin^T, zero-padded classes
    __shared__ float lg[4][16][49];           // per-wave logits
    __shared__ float blin_s[48];

    const int tid  = threadIdx.x;
    const int row0 = blockIdx.x * 64;

    for (int i = tid; i < 48 * 200; i += 256) wt[i] = 0;
    if (tid < 48) blin_s[tid] = (tid < 40) ? blin[tid] : 0.f;
    __syncthreads();  // zeros visible before sparse overwrite below
    for (int i = tid; i < 192 * 40; i += 256) {
        int k = i / 40, n = i % 40;
        wt[n * 200 + k] = f2b(Wlin[i]);
    }
    for (int i = tid; i < 64 * 64; i += 256) {
        int r = i >> 6, c = i & 63;
        int grow = row0 + r;
        bool ok = grow < Nn;
        xs[r * 200 + c]       = ok ? f2b(x1[grow * 64 + c]) : 0;
        xs[r * 200 + 64 + c]  = ok ? f2b(x2[grow * 64 + c]) : 0;
        xs[r * 200 + 128 + c] = ok ? f2b(x3[grow * 64 + c]) : 0;
    }
    __syncthreads();

    const int wv   = tid >> 6;
    const int lane = tid & 63;
    const int l15  = lane & 15;
    const int quad = lane >> 4;

    short8 a[6];
    const unsigned short* arow = xs + (wv * 16 + l15) * 200 + quad * 8;
#pragma unroll
    for (int ks = 0; ks < 6; ++ks) a[ks] = *(const short8*)(arow + ks * 32);

#pragma unroll
    for (int nt = 0; nt < 3; ++nt) {
        f32x4 acc = {0.f, 0.f, 0.f, 0.f};
        const unsigned short* brow = wt + (nt * 16 + l15) * 200 + quad * 8;
#pragma unroll
        for (int ks = 0; ks < 6; ++ks) {
            short8 b = *(const short8*)(brow + ks * 32);
            acc = __builtin_amdgcn_mfma_f32_16x16x32_bf16(a[ks], b, acc, 0, 0, 0);
        }
#pragma unroll
        for (int reg = 0; reg < 4; ++reg)
            lg[wv][quad * 4 + reg][nt * 16 + l15] = acc[reg];
    }
    // intra-wave LDS write->read: compiler inserts lgkmcnt wait; no barrier.

    // log_softmax: 4 lanes per row, 10 classes each
    const int r    = l15;
    const int part = quad;           // class chunk part*10 .. part*10+9
    float v[10];
    float mx = -INFINITY;
#pragma unroll
    for (int j = 0; j < 10; ++j) {
        v[j] = lg[wv][r][part * 10 + j] + blin_s[part * 10 + j];
        mx = fmaxf(mx, v[j]);
    }
    mx = fmaxf(mx, __shfl_xor(mx, 16));
    mx = fmaxf(mx, __shfl_xor(mx, 32));
    float s = 0.f;
#pragma unroll
    for (int j = 0; j < 10; ++j) s += expf(v[j] - mx);
    s += __shfl_xor(s, 16);
    s += __shfl_xor(s, 32);
    float lse = mx + logf(s);
    int grow = row0 + wv * 16 + r;
    if (grow < Nn) {
#pragma unroll
        for (int j = 0; j < 10; ++j)
            out[grow * NCLS + part * 10 + j] = v[j] - lse;
    }
}

// ---------------------------------------------------------------------------
extern "C" void kernel_launch(void* const* d_in, const int* in_sizes, int n_in,
                              void* d_out, int out_size, void* d_ws, size_t ws_size,
                              hipStream_t stream) {
    const float* x0  = (const float*)d_in[0];
    const int*   ei  = (const int*)d_in[1];
    const float* ew  = (const float*)d_in[2];
    const float* W1l = (const float*)d_in[3];
    const float* W1r = (const float*)d_in[4];
    const float* b1  = (const float*)d_in[5];
    const float* W2l = (const float*)d_in[6];
    const float* W2r = (const float*)d_in[7];
    const float* b2  = (const float*)d_in[8];
    const float* W3l = (const float*)d_in[9];
    const float* W3r = (const float*)d_in[10];
    const float* b3  = (const float*)d_in[11];
    const float* Wlin = (const float*)d_in[12];
    const float* blin = (const float*)d_in[13];
    float* out = (float*)d_out;

    const int* src = ei;       // edge_index[0]
    const int* dst = ei + Ee;  // edge_index[1]

    // Workspace layout (4-byte elements)
    const size_t N64 = (size_t)Nn * 64;
    char* ws = (char*)d_ws;
    int*   cnt    = (int*)ws;                       // 50048
    int*   rowptr = cnt + 50048;                    // 50048 (Nn+1 used)
    int*   cursor = rowptr + 50048;                 // 50048
    int*   colA   = cursor + 50048;                 // Ee
    float* wtA    = (float*)(colA + Ee);            // Ee
    float* yl     = wtA + Ee;                       // N64
    float* zb     = yl + N64;                       // N64
    float* x1     = zb + N64;                       // N64
    float* x2     = x1 + N64;                       // N64
    float* x3     = x2 + N64;                       // N64

    const int eblocks     = (Ee + 255) / 256;
    const int gemm_blocks = Nn / 16;       // exact
    const int row_blocks  = Nn / 4;        // gather: 4 rows/block, exact
    const int fin_blocks  = (Nn + 63) / 64;

    // ---- CSR build (per call; ws is re-poisoned) ----
    hipMemsetAsync(cnt, 0, Nn * sizeof(int), stream);
    count_kernel<<<eblocks, 256, 0, stream>>>(dst, cnt);
    scan_kernel<<<1, 1024, 0, stream>>>(cnt, rowptr, cursor);
    fill_kernel<<<eblocks, 256, 0, stream>>>(src, dst, ew, cursor, colA, wtA);

    // ---- layer 1 (K = 128) ----
    gemm2_kernel<FIN><<<gemm_blocks, 256, 0, stream>>>(x0, W1l, W1r, b1, yl, zb);
    gather_kernel<<<row_blocks, 256, 0, stream>>>(rowptr, colA, wtA, yl, zb, x1);

    // ---- layer 2 (K = 64) ----
    gemm2_kernel<HID><<<gemm_blocks, 256, 0, stream>>>(x1, W2l, W2r, b2, yl, zb);
    gather_kernel<<<row_blocks, 256, 0, stream>>>(rowptr, colA, wtA, yl, zb, x2);

    // ---- layer 3 (K = 64) ----
    gemm2_kernel<HID><<<gemm_blocks, 256, 0, stream>>>(x2, W3l, W3r, b3, yl, zb);
    gather_kernel<<<row_blocks, 256, 0, stream>>>(rowptr, colA, wtA, yl, zb, x3);

    // ---- final linear + log_softmax (bf16 MFMA) ----
    final_kernel<<<fin_blocks, 256, 0, stream>>>(x1, x2, x3, Wlin, blin, out);
}

// Round 4
// 530.395 us; speedup vs baseline: 4.0206x; 1.2089x over previous
//
#include <hip/hip_runtime.h>
#include <hip/hip_bf16.h>
#include <math.h>

// Problem constants (match reference setup_inputs)
static constexpr int Nn   = 50000;
static constexpr int Ee   = 1200000;
static constexpr int FIN  = 128;
static constexpr int HID  = 64;
static constexpr int NCLS = 40;

static constexpr int SCAN_BLOCKS = (Nn + 255) / 256;  // 196

typedef float f32x4  __attribute__((ext_vector_type(4)));
typedef short short8 __attribute__((ext_vector_type(8)));

__device__ inline unsigned short f2b(float f) {  // fp32 -> bf16 (RNE)
    unsigned int u = __builtin_bit_cast(unsigned int, f);
    return (unsigned short)((u + 0x7FFFu + ((u >> 16) & 1u)) >> 16);
}

// ---------------------------------------------------------------------------
// CSR build step 1: count in-degree (int)
__global__ __launch_bounds__(256) void count_kernel(const int* __restrict__ dst,
                                                    int* __restrict__ cnt) {
    int e = blockIdx.x * 256 + threadIdx.x;
    if (e < Ee) atomicAdd(&cnt[dst[e]], 1);
}

// CSR build step 2a: per-block (256-elem) exclusive scan, coalesced loads.
// (R3 post-mortem: single-block scan with per-thread 49-strided loads was
// uncoalesced + one-CU latency-bound: 127 us. Hierarchical + coalesced.)
__global__ __launch_bounds__(256) void scanA_kernel(const int* __restrict__ cnt,
                                                    int* __restrict__ rowptr,
                                                    int* __restrict__ bsum) {
    const int i    = blockIdx.x * 256 + threadIdx.x;
    const int lane = threadIdx.x & 63;
    const int wv   = threadIdx.x >> 6;
    int v = (i < Nn) ? cnt[i] : 0;
    int incl = v;
#pragma unroll
    for (int off = 1; off < 64; off <<= 1) {
        int t = __shfl_up(incl, off);
        if (lane >= off) incl += t;
    }
    __shared__ int wsum[4];
    if (lane == 63) wsum[wv] = incl;
    __syncthreads();
    int woff = 0;
#pragma unroll
    for (int w = 0; w < 4; ++w) woff += (w < wv) ? wsum[w] : 0;
    if (i < Nn) rowptr[i] = woff + incl - v;  // block-local exclusive
    if (threadIdx.x == 255) bsum[blockIdx.x] = woff + incl;
}

// CSR build step 2b: add block offsets (each block reduces bsum[0..b-1]),
// finalize rowptr and cursor.
__global__ __launch_bounds__(256) void scanC_kernel(int* __restrict__ rowptr,
                                                    const int* __restrict__ bsum,
                                                    int* __restrict__ cursor) {
    __shared__ int wsum[4];
    const int t    = threadIdx.x;
    const int lane = t & 63;
    const int wv   = t >> 6;
    int v = (t < blockIdx.x) ? bsum[t] : 0;  // blockIdx.x <= 195 < 256
#pragma unroll
    for (int off = 32; off; off >>= 1) v += __shfl_xor(v, off);
    if (lane == 0) wsum[wv] = v;
    __syncthreads();
    const int boff = wsum[0] + wsum[1] + wsum[2] + wsum[3];
    const int i = blockIdx.x * 256 + t;
    if (i < Nn) {
        int r = rowptr[i] + boff;
        rowptr[i] = r;
        cursor[i] = r;
    }
    if (blockIdx.x == 0 && t == 0) rowptr[Nn] = Ee;
}

// CSR build step 3: scatter edges into slots
__global__ __launch_bounds__(256) void fill_kernel(
    const int* __restrict__ src, const int* __restrict__ dst,
    const float* __restrict__ ew, int* __restrict__ cursor,
    int* __restrict__ colA, float* __restrict__ wtA) {
    int e = blockIdx.x * 256 + threadIdx.x;
    if (e < Ee) {
        int d = dst[e];
        int p = atomicAdd(&cursor[d], 1);
        colA[p] = src[e];
        wtA[p]  = ew[e];
    }
}

// ---------------------------------------------------------------------------
// Fused dual GEMM: yl = x @ Wl ; z = x @ Wr + b   (x: [n,K], W: [K,64])
// 16 rows/block, 256 threads. k-loop kept rolled to avoid register spills
// (R1 post-mortem: full unroll -> 256 VGPR + 862MB scratch traffic).
template <int K>
__global__ __launch_bounds__(256, 4) void gemm2_kernel(
    const float* __restrict__ x, const float* __restrict__ Wl,
    const float* __restrict__ Wr, const float* __restrict__ b,
    float* __restrict__ yl, float* __restrict__ z) {
    __shared__ float w_s[2][64 * 64];  // 32 KB
    __shared__ float x_s[16][K];
    const int col  = threadIdx.x & 63;
    const int half = (threadIdx.x >> 6) & 1;  // 0 -> yl, 1 -> z
    const int rh   = threadIdx.x >> 7;        // 0..1
    const int row0 = blockIdx.x * 16;

    for (int i = threadIdx.x; i < 16 * K; i += 256) {
        int r = i / K, c = i % K;
        x_s[r][c] = x[(row0 + r) * K + c];
    }

    float acc[8];
#pragma unroll
    for (int i = 0; i < 8; ++i) acc[i] = 0.f;

    for (int kt = 0; kt < K; kt += 64) {
        __syncthreads();
        for (int i = threadIdx.x; i < 64 * 64; i += 256) {
            int kr = i >> 6, kc = i & 63;
            w_s[0][i] = Wl[(kt + kr) * 64 + kc];
            w_s[1][i] = Wr[(kt + kr) * 64 + kc];
        }
        __syncthreads();
#pragma unroll 2
        for (int k4 = 0; k4 < 64; k4 += 4) {
            float w0 = w_s[half][(k4 + 0) * 64 + col];
            float w1 = w_s[half][(k4 + 1) * 64 + col];
            float w2 = w_s[half][(k4 + 2) * 64 + col];
            float w3 = w_s[half][(k4 + 3) * 64 + col];
#pragma unroll
            for (int r = 0; r < 8; ++r) {
                const float4 xv = *(const float4*)&x_s[rh * 8 + r][kt + k4];
                acc[r] += xv.x * w0 + xv.y * w1 + xv.z * w2 + xv.w * w3;
            }
        }
    }

    const float bias = b[col];
    float* __restrict__ outp = half ? z : yl;
#pragma unroll
    for (int r = 0; r < 8; ++r) {
        int row = row0 + rh * 8 + r;
        outp[row * 64 + col] = acc[r] + (half ? bias : 0.f);
    }
}

// ---------------------------------------------------------------------------
// Pull-mode aggregation + finish, fused: one wave per dst row, lane = feature.
__global__ __launch_bounds__(256) void gather_kernel(
    const int* __restrict__ rowptr, const int* __restrict__ colA,
    const float* __restrict__ wtA, const float* __restrict__ yl,
    const float* __restrict__ z, float* __restrict__ xout) {
    int row  = (blockIdx.x * 256 + threadIdx.x) >> 6;
    int lane = threadIdx.x & 63;
    int beg = rowptr[row], end = rowptr[row + 1];
    float acc = 0.f;
    int e = beg;
    for (; e + 4 <= end; e += 4) {
        int   s0 = colA[e],   s1 = colA[e + 1],   s2 = colA[e + 2],   s3 = colA[e + 3];
        float w0 = wtA[e],    w1 = wtA[e + 1],    w2 = wtA[e + 2],    w3 = wtA[e + 3];
        float v0 = yl[s0 * 64 + lane], v1 = yl[s1 * 64 + lane];
        float v2 = yl[s2 * 64 + lane], v3 = yl[s3 * 64 + lane];
        acc += v0 * w0; acc += v1 * w1; acc += v2 * w2; acc += v3 * w3;
    }
    for (; e < end; ++e) acc += yl[colA[e] * 64 + lane] * wtA[e];
    float deg = (float)(end - beg);
    float v = acc / fmaxf(deg, 1.f) + z[row * 64 + lane];
    xout[row * 64 + lane] = fmaxf(v, 0.f);
}

// ---------------------------------------------------------------------------
// Final: logits = [x1|x2|x3] @ Wlin + blin; out = log_softmax(logits).
// bf16 MFMA GEMM: block = 64 rows (4 waves x 16), N padded 40->48, K=192.
// A-layout: A[m=lane&15][k=(lane>>4)*8+j]; C/D: col=lane&15, row=quad*4+reg.
__global__ __launch_bounds__(256) void final_kernel(
    const float* __restrict__ x1, const float* __restrict__ x2,
    const float* __restrict__ x3, const float* __restrict__ Wlin,
    const float* __restrict__ blin, float* __restrict__ out) {
    __shared__ unsigned short xs[64 * 200];   // 64 rows x 192 (stride 200)
    __shared__ unsigned short wt[48 * 200];   // Wlin^T, zero-padded classes
    __shared__ float lg[4][16][49];           // per-wave logits
    __shared__ float blin_s[48];

    const int tid  = threadIdx.x;
    const int row0 = blockIdx.x * 64;

    for (int i = tid; i < 48 * 200; i += 256) wt[i] = 0;
    if (tid < 48) blin_s[tid] = (tid < 40) ? blin[tid] : 0.f;
    __syncthreads();  // zeros visible before sparse overwrite below
    for (int i = tid; i < 192 * 40; i += 256) {
        int k = i / 40, n = i % 40;
        wt[n * 200 + k] = f2b(Wlin[i]);
    }
    for (int i = tid; i < 64 * 64; i += 256) {
        int r = i >> 6, c = i & 63;
        int grow = row0 + r;
        bool ok = grow < Nn;
        xs[r * 200 + c]       = ok ? f2b(x1[grow * 64 + c]) : 0;
        xs[r * 200 + 64 + c]  = ok ? f2b(x2[grow * 64 + c]) : 0;
        xs[r * 200 + 128 + c] = ok ? f2b(x3[grow * 64 + c]) : 0;
    }
    __syncthreads();

    const int wv   = tid >> 6;
    const int lane = tid & 63;
    const int l15  = lane & 15;
    const int quad = lane >> 4;

    short8 a[6];
    const unsigned short* arow = xs + (wv * 16 + l15) * 200 + quad * 8;
#pragma unroll
    for (int ks = 0; ks < 6; ++ks) a[ks] = *(const short8*)(arow + ks * 32);

#pragma unroll
    for (int nt = 0; nt < 3; ++nt) {
        f32x4 acc = {0.f, 0.f, 0.f, 0.f};
        const unsigned short* brow = wt + (nt * 16 + l15) * 200 + quad * 8;
#pragma unroll
        for (int ks = 0; ks < 6; ++ks) {
            short8 b = *(const short8*)(brow + ks * 32);
            acc = __builtin_amdgcn_mfma_f32_16x16x32_bf16(a[ks], b, acc, 0, 0, 0);
        }
#pragma unroll
        for (int reg = 0; reg < 4; ++reg)
            lg[wv][quad * 4 + reg][nt * 16 + l15] = acc[reg];
    }
    // intra-wave LDS write->read: compiler inserts lgkmcnt wait; no barrier.

    // log_softmax: 4 lanes per row, 10 classes each
    const int r    = l15;
    const int part = quad;           // class chunk part*10 .. part*10+9
    float v[10];
    float mx = -INFINITY;
#pragma unroll
    for (int j = 0; j < 10; ++j) {
        v[j] = lg[wv][r][part * 10 + j] + blin_s[part * 10 + j];
        mx = fmaxf(mx, v[j]);
    }
    mx = fmaxf(mx, __shfl_xor(mx, 16));
    mx = fmaxf(mx, __shfl_xor(mx, 32));
    float s = 0.f;
#pragma unroll
    for (int j = 0; j < 10; ++j) s += expf(v[j] - mx);
    s += __shfl_xor(s, 16);
    s += __shfl_xor(s, 32);
    float lse = mx + logf(s);
    int grow = row0 + wv * 16 + r;
    if (grow < Nn) {
#pragma unroll
        for (int j = 0; j < 10; ++j)
            out[grow * NCLS + part * 10 + j] = v[j] - lse;
    }
}

// ---------------------------------------------------------------------------
extern "C" void kernel_launch(void* const* d_in, const int* in_sizes, int n_in,
                              void* d_out, int out_size, void* d_ws, size_t ws_size,
                              hipStream_t stream) {
    const float* x0  = (const float*)d_in[0];
    const int*   ei  = (const int*)d_in[1];
    const float* ew  = (const float*)d_in[2];
    const float* W1l = (const float*)d_in[3];
    const float* W1r = (const float*)d_in[4];
    const float* b1  = (const float*)d_in[5];
    const float* W2l = (const float*)d_in[6];
    const float* W2r = (const float*)d_in[7];
    const float* b2  = (const float*)d_in[8];
    const float* W3l = (const float*)d_in[9];
    const float* W3r = (const float*)d_in[10];
    const float* b3  = (const float*)d_in[11];
    const float* Wlin = (const float*)d_in[12];
    const float* blin = (const float*)d_in[13];
    float* out = (float*)d_out;

    const int* src = ei;       // edge_index[0]
    const int* dst = ei + Ee;  // edge_index[1]

    // Workspace layout (4-byte elements)
    const size_t N64 = (size_t)Nn * 64;
    char* ws = (char*)d_ws;
    int*   cnt    = (int*)ws;                       // 50048
    int*   rowptr = cnt + 50048;                    // 50048 (Nn+1 used)
    int*   cursor = rowptr + 50048;                 // 50048
    int*   bsum   = cursor + 50048;                 // 256 (196 used)
    int*   colA   = bsum + 256;                     // Ee
    float* wtA    = (float*)(colA + Ee);            // Ee
    float* yl     = wtA + Ee;                       // N64
    float* zb     = yl + N64;                       // N64
    float* x1     = zb + N64;                       // N64
    float* x2     = x1 + N64;                       // N64
    float* x3     = x2 + N64;                       // N64

    const int eblocks     = (Ee + 255) / 256;
    const int gemm_blocks = Nn / 16;       // exact
    const int row_blocks  = Nn / 4;        // gather: 4 rows/block, exact
    const int fin_blocks  = (Nn + 63) / 64;

    // ---- CSR build (per call; ws is re-poisoned) ----
    hipMemsetAsync(cnt, 0, Nn * sizeof(int), stream);
    count_kernel<<<eblocks, 256, 0, stream>>>(dst, cnt);
    scanA_kernel<<<SCAN_BLOCKS, 256, 0, stream>>>(cnt, rowptr, bsum);
    scanC_kernel<<<SCAN_BLOCKS, 256, 0, stream>>>(rowptr, bsum, cursor);
    fill_kernel<<<eblocks, 256, 0, stream>>>(src, dst, ew, cursor, colA, wtA);

    // ---- layer 1 (K = 128) ----
    gemm2_kernel<FIN><<<gemm_blocks, 256, 0, stream>>>(x0, W1l, W1r, b1, yl, zb);
    gather_kernel<<<row_blocks, 256, 0, stream>>>(rowptr, colA, wtA, yl, zb, x1);

    // ---- layer 2 (K = 64) ----
    gemm2_kernel<HID><<<gemm_blocks, 256, 0, stream>>>(x1, W2l, W2r, b2, yl, zb);
    gather_kernel<<<row_blocks, 256, 0, stream>>>(rowptr, colA, wtA, yl, zb, x2);

    // ---- layer 3 (K = 64) ----
    gemm2_kernel<HID><<<gemm_blocks, 256, 0, stream>>>(x2, W3l, W3r, b3, yl, zb);
    gather_kernel<<<row_blocks, 256, 0, stream>>>(rowptr, colA, wtA, yl, zb, x3);

    // ---- final linear + log_softmax (bf16 MFMA) ----
    final_kernel<<<fin_blocks, 256, 0, stream>>>(x1, x2, x3, Wlin, blin, out);
}

// Round 5
// 513.118 us; speedup vs baseline: 4.1560x; 1.0337x over previous
//
#include <hip/hip_runtime.h>
#include <hip/hip_bf16.h>
#include <math.h>

// Problem constants (match reference setup_inputs)
static constexpr int Nn   = 50000;
static constexpr int Ee   = 1200000;
static constexpr int FIN  = 128;
static constexpr int HID  = 64;
static constexpr int NCLS = 40;

static constexpr int SCAN_BLOCKS = (Nn + 255) / 256;  // 196

typedef float f32x4  __attribute__((ext_vector_type(4)));
typedef short short8 __attribute__((ext_vector_type(8)));

__device__ inline unsigned short f2b(float f) {  // fp32 -> bf16 (RNE)
    unsigned int u = __builtin_bit_cast(unsigned int, f);
    return (unsigned short)((u + 0x7FFFu + ((u >> 16) & 1u)) >> 16);
}

// ---------------------------------------------------------------------------
// CSR build step 1: count in-degree (int)
__global__ __launch_bounds__(256) void count_kernel(const int* __restrict__ dst,
                                                    int* __restrict__ cnt) {
    int e = blockIdx.x * 256 + threadIdx.x;
    if (e < Ee) atomicAdd(&cnt[dst[e]], 1);
}

// CSR build step 2a: per-block (256-elem) exclusive scan, coalesced loads.
// (R3 post-mortem: single-block strided scan was 127 us; hierarchical fix.)
__global__ __launch_bounds__(256) void scanA_kernel(const int* __restrict__ cnt,
                                                    int* __restrict__ rowptr,
                                                    int* __restrict__ bsum) {
    const int i    = blockIdx.x * 256 + threadIdx.x;
    const int lane = threadIdx.x & 63;
    const int wv   = threadIdx.x >> 6;
    int v = (i < Nn) ? cnt[i] : 0;
    int incl = v;
#pragma unroll
    for (int off = 1; off < 64; off <<= 1) {
        int t = __shfl_up(incl, off);
        if (lane >= off) incl += t;
    }
    __shared__ int wsum[4];
    if (lane == 63) wsum[wv] = incl;
    __syncthreads();
    int woff = 0;
#pragma unroll
    for (int w = 0; w < 4; ++w) woff += (w < wv) ? wsum[w] : 0;
    if (i < Nn) rowptr[i] = woff + incl - v;  // block-local exclusive
    if (threadIdx.x == 255) bsum[blockIdx.x] = woff + incl;
}

// CSR build step 2b: add block offsets, finalize rowptr and cursor.
__global__ __launch_bounds__(256) void scanC_kernel(int* __restrict__ rowptr,
                                                    const int* __restrict__ bsum,
                                                    int* __restrict__ cursor) {
    __shared__ int wsum[4];
    const int t    = threadIdx.x;
    const int lane = t & 63;
    const int wv   = t >> 6;
    int v = (t < blockIdx.x) ? bsum[t] : 0;  // blockIdx.x <= 195 < 256
#pragma unroll
    for (int off = 32; off; off >>= 1) v += __shfl_xor(v, off);
    if (lane == 0) wsum[wv] = v;
    __syncthreads();
    const int boff = wsum[0] + wsum[1] + wsum[2] + wsum[3];
    const int i = blockIdx.x * 256 + t;
    if (i < Nn) {
        int r = rowptr[i] + boff;
        rowptr[i] = r;
        cursor[i] = r;
    }
    if (blockIdx.x == 0 && t == 0) rowptr[Nn] = Ee;
}

// CSR build step 3: scatter edges into slots.
// R4 post-mortem: two 4B scattered stores (colA/wtA) cost 113MB HBM writes
// (~one line-event per store, no temporal reuse). Pack (src, wt) into one
// int2 -> single 8B scattered store per edge -> half the line-touch events.
__global__ __launch_bounds__(256) void fill_kernel(
    const int* __restrict__ src, const int* __restrict__ dst,
    const float* __restrict__ ew, int* __restrict__ cursor,
    int2* __restrict__ edgeA) {
    int e = blockIdx.x * 256 + threadIdx.x;
    if (e < Ee) {
        int d = dst[e];
        int p = atomicAdd(&cursor[d], 1);
        edgeA[p] = make_int2(src[e], __builtin_bit_cast(int, ew[e]));
    }
}

// ---------------------------------------------------------------------------
// Fused dual GEMM: yl = x @ Wl ; z = x @ Wr + b   (x: [n,K], W: [K,64])
// 16 rows/block, 256 threads. k-loop kept rolled to avoid register spills
// (R1 post-mortem: full unroll -> 256 VGPR + 862MB scratch traffic).
template <int K>
__global__ __launch_bounds__(256, 4) void gemm2_kernel(
    const float* __restrict__ x, const float* __restrict__ Wl,
    const float* __restrict__ Wr, const float* __restrict__ b,
    float* __restrict__ yl, float* __restrict__ z) {
    __shared__ float w_s[2][64 * 64];  // 32 KB
    __shared__ float x_s[16][K];
    const int col  = threadIdx.x & 63;
    const int half = (threadIdx.x >> 6) & 1;  // 0 -> yl, 1 -> z
    const int rh   = threadIdx.x >> 7;        // 0..1
    const int row0 = blockIdx.x * 16;

    for (int i = threadIdx.x; i < 16 * K; i += 256) {
        int r = i / K, c = i % K;
        x_s[r][c] = x[(row0 + r) * K + c];
    }

    float acc[8];
#pragma unroll
    for (int i = 0; i < 8; ++i) acc[i] = 0.f;

    for (int kt = 0; kt < K; kt += 64) {
        __syncthreads();
        for (int i = threadIdx.x; i < 64 * 64; i += 256) {
            int kr = i >> 6, kc = i & 63;
            w_s[0][i] = Wl[(kt + kr) * 64 + kc];
            w_s[1][i] = Wr[(kt + kr) * 64 + kc];
        }
        __syncthreads();
#pragma unroll 2
        for (int k4 = 0; k4 < 64; k4 += 4) {
            float w0 = w_s[half][(k4 + 0) * 64 + col];
            float w1 = w_s[half][(k4 + 1) * 64 + col];
            float w2 = w_s[half][(k4 + 2) * 64 + col];
            float w3 = w_s[half][(k4 + 3) * 64 + col];
#pragma unroll
            for (int r = 0; r < 8; ++r) {
                const float4 xv = *(const float4*)&x_s[rh * 8 + r][kt + k4];
                acc[r] += xv.x * w0 + xv.y * w1 + xv.z * w2 + xv.w * w3;
            }
        }
    }

    const float bias = b[col];
    float* __restrict__ outp = half ? z : yl;
#pragma unroll
    for (int r = 0; r < 8; ++r) {
        int row = row0 + rh * 8 + r;
        outp[row * 64 + col] = acc[r] + (half ? bias : 0.f);
    }
}

// ---------------------------------------------------------------------------
// Pull-mode aggregation + finish, fused: one wave per dst row, lane = feature.
__global__ __launch_bounds__(256) void gather_kernel(
    const int* __restrict__ rowptr, const int2* __restrict__ edgeA,
    const float* __restrict__ yl, const float* __restrict__ z,
    float* __restrict__ xout) {
    int row  = (blockIdx.x * 256 + threadIdx.x) >> 6;
    int lane = threadIdx.x & 63;
    int beg = rowptr[row], end = rowptr[row + 1];
    float acc = 0.f;
    int e = beg;
    for (; e + 4 <= end; e += 4) {
        int2 e0 = edgeA[e],     e1 = edgeA[e + 1];
        int2 e2 = edgeA[e + 2], e3 = edgeA[e + 3];
        float v0 = yl[e0.x * 64 + lane], v1 = yl[e1.x * 64 + lane];
        float v2 = yl[e2.x * 64 + lane], v3 = yl[e3.x * 64 + lane];
        acc += v0 * __builtin_bit_cast(float, e0.y);
        acc += v1 * __builtin_bit_cast(float, e1.y);
        acc += v2 * __builtin_bit_cast(float, e2.y);
        acc += v3 * __builtin_bit_cast(float, e3.y);
    }
    for (; e < end; ++e) {
        int2 ee = edgeA[e];
        acc += yl[ee.x * 64 + lane] * __builtin_bit_cast(float, ee.y);
    }
    float deg = (float)(end - beg);
    float v = acc / fmaxf(deg, 1.f) + z[row * 64 + lane];
    xout[row * 64 + lane] = fmaxf(v, 0.f);
}

// ---------------------------------------------------------------------------
// Final: logits = [x1|x2|x3] @ Wlin + blin; out = log_softmax(logits).
// bf16 MFMA GEMM: block = 64 rows (4 waves x 16), N padded 40->48, K=192.
// A-layout: A[m=lane&15][k=(lane>>4)*8+j]; C/D: col=lane&15, row=quad*4+reg.
__global__ __launch_bounds__(256) void final_kernel(
    const float* __restrict__ x1, const float* __restrict__ x2,
    const float* __restrict__ x3, const float* __restrict__ Wlin,
    const float* __restrict__ blin, float* __restrict__ out) {
    __shared__ unsigned short xs[64 * 200];   // 64 rows x 192 (stride 200)
    __shared__ unsigned short wt[48 * 200];   // Wlin^T, zero-padded classes
    __shared__ float lg[4][16][49];           // per-wave logits
    __shared__ float blin_s[48];

    const int tid  = threadIdx.x;
    const int row0 = blockIdx.x * 64;

    for (int i = tid; i < 48 * 200; i += 256) wt[i] = 0;
    if (tid < 48) blin_s[tid] = (tid < 40) ? blin[tid] : 0.f;
    __syncthreads();  // zeros visible before sparse overwrite below
    for (int i = tid; i < 192 * 40; i += 256) {
        int k = i / 40, n = i % 40;
        wt[n * 200 + k] = f2b(Wlin[i]);
    }
    for (int i = tid; i < 64 * 64; i += 256) {
        int r = i >> 6, c = i & 63;
        int grow = row0 + r;
        bool ok = grow < Nn;
        xs[r * 200 + c]       = ok ? f2b(x1[grow * 64 + c]) : 0;
        xs[r * 200 + 64 + c]  = ok ? f2b(x2[grow * 64 + c]) : 0;
        xs[r * 200 + 128 + c] = ok ? f2b(x3[grow * 64 + c]) : 0;
    }
    __syncthreads();

    const int wv   = tid >> 6;
    const int lane = tid & 63;
    const int l15  = lane & 15;
    const int quad = lane >> 4;

    short8 a[6];
    const unsigned short* arow = xs + (wv * 16 + l15) * 200 + quad * 8;
#pragma unroll
    for (int ks = 0; ks < 6; ++ks) a[ks] = *(const short8*)(arow + ks * 32);

#pragma unroll
    for (int nt = 0; nt < 3; ++nt) {
        f32x4 acc = {0.f, 0.f, 0.f, 0.f};
        const unsigned short* brow = wt + (nt * 16 + l15) * 200 + quad * 8;
#pragma unroll
        for (int ks = 0; ks < 6; ++ks) {
            short8 b = *(const short8*)(brow + ks * 32);
            acc = __builtin_amdgcn_mfma_f32_16x16x32_bf16(a[ks], b, acc, 0, 0, 0);
        }
#pragma unroll
        for (int reg = 0; reg < 4; ++reg)
            lg[wv][quad * 4 + reg][nt * 16 + l15] = acc[reg];
    }
    // intra-wave LDS write->read: compiler inserts lgkmcnt wait; no barrier.

    // log_softmax: 4 lanes per row, 10 classes each
    const int r    = l15;
    const int part = quad;           // class chunk part*10 .. part*10+9
    float v[10];
    float mx = -INFINITY;
#pragma unroll
    for (int j = 0; j < 10; ++j) {
        v[j] = lg[wv][r][part * 10 + j] + blin_s[part * 10 + j];
        mx = fmaxf(mx, v[j]);
    }
    mx = fmaxf(mx, __shfl_xor(mx, 16));
    mx = fmaxf(mx, __shfl_xor(mx, 32));
    float s = 0.f;
#pragma unroll
    for (int j = 0; j < 10; ++j) s += expf(v[j] - mx);
    s += __shfl_xor(s, 16);
    s += __shfl_xor(s, 32);
    float lse = mx + logf(s);
    int grow = row0 + wv * 16 + r;
    if (grow < Nn) {
#pragma unroll
        for (int j = 0; j < 10; ++j)
            out[grow * NCLS + part * 10 + j] = v[j] - lse;
    }
}

// ---------------------------------------------------------------------------
extern "C" void kernel_launch(void* const* d_in, const int* in_sizes, int n_in,
                              void* d_out, int out_size, void* d_ws, size_t ws_size,
                              hipStream_t stream) {
    const float* x0  = (const float*)d_in[0];
    const int*   ei  = (const int*)d_in[1];
    const float* ew  = (const float*)d_in[2];
    const float* W1l = (const float*)d_in[3];
    const float* W1r = (const float*)d_in[4];
    const float* b1  = (const float*)d_in[5];
    const float* W2l = (const float*)d_in[6];
    const float* W2r = (const float*)d_in[7];
    const float* b2  = (const float*)d_in[8];
    const float* W3l = (const float*)d_in[9];
    const float* W3r = (const float*)d_in[10];
    const float* b3  = (const float*)d_in[11];
    const float* Wlin = (const float*)d_in[12];
    const float* blin = (const float*)d_in[13];
    float* out = (float*)d_out;

    const int* src = ei;       // edge_index[0]
    const int* dst = ei + Ee;  // edge_index[1]

    // Workspace layout (4-byte elements; edgeA 8-byte aligned by construction)
    const size_t N64 = (size_t)Nn * 64;
    char* ws = (char*)d_ws;
    int*   cnt    = (int*)ws;                       // 50048
    int*   rowptr = cnt + 50048;                    // 50048 (Nn+1 used)
    int*   cursor = rowptr + 50048;                 // 50048
    int*   bsum   = cursor + 50048;                 // 256 (196 used)
    int2*  edgeA  = (int2*)(bsum + 256);            // Ee (8B each)
    float* yl     = (float*)(edgeA + Ee);           // N64
    float* zb     = yl + N64;                       // N64
    float* x1     = zb + N64;                       // N64
    float* x2     = x1 + N64;                       // N64
    float* x3     = x2 + N64;                       // N64

    const int eblocks     = (Ee + 255) / 256;
    const int gemm_blocks = Nn / 16;       // exact
    const int row_blocks  = Nn / 4;        // gather: 4 rows/block, exact
    const int fin_blocks  = (Nn + 63) / 64;

    // ---- CSR build (per call; ws is re-poisoned) ----
    hipMemsetAsync(cnt, 0, Nn * sizeof(int), stream);
    count_kernel<<<eblocks, 256, 0, stream>>>(dst, cnt);
    scanA_kernel<<<SCAN_BLOCKS, 256, 0, stream>>>(cnt, rowptr, bsum);
    scanC_kernel<<<SCAN_BLOCKS, 256, 0, stream>>>(rowptr, bsum, cursor);
    fill_kernel<<<eblocks, 256, 0, stream>>>(src, dst, ew, cursor, edgeA);

    // ---- layer 1 (K = 128) ----
    gemm2_kernel<FIN><<<gemm_blocks, 256, 0, stream>>>(x0, W1l, W1r, b1, yl, zb);
    gather_kernel<<<row_blocks, 256, 0, stream>>>(rowptr, edgeA, yl, zb, x1);

    // ---- layer 2 (K = 64) ----
    gemm2_kernel<HID><<<gemm_blocks, 256, 0, stream>>>(x1, W2l, W2r, b2, yl, zb);
    gather_kernel<<<row_blocks, 256, 0, stream>>>(rowptr, edgeA, yl, zb, x2);

    // ---- layer 3 (K = 64) ----
    gemm2_kernel<HID><<<gemm_blocks, 256, 0, stream>>>(x2, W3l, W3r, b3, yl, zb);
    gather_kernel<<<row_blocks, 256, 0, stream>>>(rowptr, edgeA, yl, zb, x3);

    // ---- final linear + log_softmax (bf16 MFMA) ----
    final_kernel<<<fin_blocks, 256, 0, stream>>>(x1, x2, x3, Wlin, blin, out);
}

// Round 6
// 501.216 us; speedup vs baseline: 4.2547x; 1.0237x over previous
//
#include <hip/hip_runtime.h>
#include <hip/hip_bf16.h>
#include <math.h>

// Problem constants (match reference setup_inputs)
static constexpr int Nn   = 50000;
static constexpr int Ee   = 1200000;
static constexpr int FIN  = 128;
static constexpr int HID  = 64;
static constexpr int NCLS = 40;

static constexpr int SCAN_BLOCKS = (Nn + 255) / 256;  // 196

// fill partitioning: 8 dst-ranges -> 8 XCDs via blockIdx%8 heuristic
static constexpr int NPART  = 8;
static constexpr int PROWS  = Nn / NPART;   // 6250
static constexpr int SLICES = 64;           // edge-list slices per partition
static constexpr int ESLICE = Ee / SLICES;  // 18750

typedef float f32x4  __attribute__((ext_vector_type(4)));
typedef short short8 __attribute__((ext_vector_type(8)));

__device__ inline unsigned short f2b(float f) {  // fp32 -> bf16 (RNE)
    unsigned int u = __builtin_bit_cast(unsigned int, f);
    return (unsigned short)((u + 0x7FFFu + ((u >> 16) & 1u)) >> 16);
}

// ---------------------------------------------------------------------------
// CSR build step 1: count in-degree (int)
__global__ __launch_bounds__(256) void count_kernel(const int* __restrict__ dst,
                                                    int* __restrict__ cnt) {
    int e = blockIdx.x * 256 + threadIdx.x;
    if (e < Ee) atomicAdd(&cnt[dst[e]], 1);
}

// CSR build step 2a: per-block (256-elem) exclusive scan, coalesced loads.
// (R3 post-mortem: single-block strided scan was 127 us; hierarchical fix.)
__global__ __launch_bounds__(256) void scanA_kernel(const int* __restrict__ cnt,
                                                    int* __restrict__ rowptr,
                                                    int* __restrict__ bsum) {
    const int i    = blockIdx.x * 256 + threadIdx.x;
    const int lane = threadIdx.x & 63;
    const int wv   = threadIdx.x >> 6;
    int v = (i < Nn) ? cnt[i] : 0;
    int incl = v;
#pragma unroll
    for (int off = 1; off < 64; off <<= 1) {
        int t = __shfl_up(incl, off);
        if (lane >= off) incl += t;
    }
    __shared__ int wsum[4];
    if (lane == 63) wsum[wv] = incl;
    __syncthreads();
    int woff = 0;
#pragma unroll
    for (int w = 0; w < 4; ++w) woff += (w < wv) ? wsum[w] : 0;
    if (i < Nn) rowptr[i] = woff + incl - v;  // block-local exclusive
    if (threadIdx.x == 255) bsum[blockIdx.x] = woff + incl;
}

// CSR build step 2b: add block offsets, finalize rowptr and cursor.
__global__ __launch_bounds__(256) void scanC_kernel(int* __restrict__ rowptr,
                                                    const int* __restrict__ bsum,
                                                    int* __restrict__ cursor) {
    __shared__ int wsum[4];
    const int t    = threadIdx.x;
    const int lane = t & 63;
    const int wv   = t >> 6;
    int v = (t < blockIdx.x) ? bsum[t] : 0;  // blockIdx.x <= 195 < 256
#pragma unroll
    for (int off = 32; off; off >>= 1) v += __shfl_xor(v, off);
    if (lane == 0) wsum[wv] = v;
    __syncthreads();
    const int boff = wsum[0] + wsum[1] + wsum[2] + wsum[3];
    const int i = blockIdx.x * 256 + t;
    if (i < Nn) {
        int r = rowptr[i] + boff;
        rowptr[i] = r;
        cursor[i] = r;
    }
    if (blockIdx.x == 0 && t == 0) rowptr[Nn] = Ee;
}

// CSR build step 3: scatter edges into slots, XCD-partitioned.
// R5 post-mortem: slot lines claimed at random times from random XCDs ->
// one 64B writeback per 8B store (76MB = 1.2M x 64B). Fix: partition dst
// space 8 ways, map partition -> XCD via blockIdx%8 (locality heuristic,
// correctness-independent). All stores+cursor atomics for a slot region
// then come from one XCD's L2: lines absorb all ~8 stores, write back once.
__global__ __launch_bounds__(256) void fill_kernel(
    const int* __restrict__ src, const int* __restrict__ dst,
    const float* __restrict__ ew, int* __restrict__ cursor,
    int2* __restrict__ edgeA) {
    const int part  = blockIdx.x & (NPART - 1);  // XCD id heuristic
    const int slice = blockIdx.x >> 3;           // 0..SLICES-1
    const int lo = part * PROWS, hi = lo + PROWS;
    const int e0 = slice * ESLICE, e1 = e0 + ESLICE;
    for (int e = e0 + threadIdx.x; e < e1; e += 256) {
        int d = dst[e];
        if (d >= lo && d < hi) {
            int p = atomicAdd(&cursor[d], 1);
            edgeA[p] = make_int2(src[e], __builtin_bit_cast(int, ew[e]));
        }
    }
}

// ---------------------------------------------------------------------------
// Fused dual GEMM: yl = x @ Wl ; z = x @ Wr + b   (x: [n,K], W: [K,64])
// 16 rows/block, 256 threads. k-loop kept rolled to avoid register spills
// (R1 post-mortem: full unroll -> 256 VGPR + 862MB scratch traffic).
template <int K>
__global__ __launch_bounds__(256, 4) void gemm2_kernel(
    const float* __restrict__ x, const float* __restrict__ Wl,
    const float* __restrict__ Wr, const float* __restrict__ b,
    float* __restrict__ yl, float* __restrict__ z) {
    __shared__ float w_s[2][64 * 64];  // 32 KB
    __shared__ float x_s[16][K];
    const int col  = threadIdx.x & 63;
    const int half = (threadIdx.x >> 6) & 1;  // 0 -> yl, 1 -> z
    const int rh   = threadIdx.x >> 7;        // 0..1
    const int row0 = blockIdx.x * 16;

    for (int i = threadIdx.x; i < 16 * K; i += 256) {
        int r = i / K, c = i % K;
        x_s[r][c] = x[(row0 + r) * K + c];
    }

    float acc[8];
#pragma unroll
    for (int i = 0; i < 8; ++i) acc[i] = 0.f;

    for (int kt = 0; kt < K; kt += 64) {
        __syncthreads();
        for (int i = threadIdx.x; i < 64 * 64; i += 256) {
            int kr = i >> 6, kc = i & 63;
            w_s[0][i] = Wl[(kt + kr) * 64 + kc];
            w_s[1][i] = Wr[(kt + kr) * 64 + kc];
        }
        __syncthreads();
#pragma unroll 2
        for (int k4 = 0; k4 < 64; k4 += 4) {
            float w0 = w_s[half][(k4 + 0) * 64 + col];
            float w1 = w_s[half][(k4 + 1) * 64 + col];
            float w2 = w_s[half][(k4 + 2) * 64 + col];
            float w3 = w_s[half][(k4 + 3) * 64 + col];
#pragma unroll
            for (int r = 0; r < 8; ++r) {
                const float4 xv = *(const float4*)&x_s[rh * 8 + r][kt + k4];
                acc[r] += xv.x * w0 + xv.y * w1 + xv.z * w2 + xv.w * w3;
            }
        }
    }

    const float bias = b[col];
    float* __restrict__ outp = half ? z : yl;
#pragma unroll
    for (int r = 0; r < 8; ++r) {
        int row = row0 + rh * 8 + r;
        outp[row * 64 + col] = acc[r] + (half ? bias : 0.f);
    }
}

// ---------------------------------------------------------------------------
// Pull-mode aggregation + finish, fused: one wave per dst row, lane = feature.
__global__ __launch_bounds__(256) void gather_kernel(
    const int* __restrict__ rowptr, const int2* __restrict__ edgeA,
    const float* __restrict__ yl, const float* __restrict__ z,
    float* __restrict__ xout) {
    int row  = (blockIdx.x * 256 + threadIdx.x) >> 6;
    int lane = threadIdx.x & 63;
    int beg = rowptr[row], end = rowptr[row + 1];
    float acc = 0.f;
    int e = beg;
    for (; e + 4 <= end; e += 4) {
        int2 e0 = edgeA[e],     e1 = edgeA[e + 1];
        int2 e2 = edgeA[e + 2], e3 = edgeA[e + 3];
        float v0 = yl[e0.x * 64 + lane], v1 = yl[e1.x * 64 + lane];
        float v2 = yl[e2.x * 64 + lane], v3 = yl[e3.x * 64 + lane];
        acc += v0 * __builtin_bit_cast(float, e0.y);
        acc += v1 * __builtin_bit_cast(float, e1.y);
        acc += v2 * __builtin_bit_cast(float, e2.y);
        acc += v3 * __builtin_bit_cast(float, e3.y);
    }
    for (; e < end; ++e) {
        int2 ee = edgeA[e];
        acc += yl[ee.x * 64 + lane] * __builtin_bit_cast(float, ee.y);
    }
    float deg = (float)(end - beg);
    float v = acc / fmaxf(deg, 1.f) + z[row * 64 + lane];
    xout[row * 64 + lane] = fmaxf(v, 0.f);
}

// ---------------------------------------------------------------------------
// Final: logits = [x1|x2|x3] @ Wlin + blin; out = log_softmax(logits).
// bf16 MFMA GEMM: block = 64 rows (4 waves x 16), N padded 40->48, K=192.
// A-layout: A[m=lane&15][k=(lane>>4)*8+j]; C/D: col=lane&15, row=quad*4+reg.
__global__ __launch_bounds__(256) void final_kernel(
    const float* __restrict__ x1, const float* __restrict__ x2,
    const float* __restrict__ x3, const float* __restrict__ Wlin,
    const float* __restrict__ blin, float* __restrict__ out) {
    __shared__ unsigned short xs[64 * 200];   // 64 rows x 192 (stride 200)
    __shared__ unsigned short wt[48 * 200];   // Wlin^T, zero-padded classes
    __shared__ float lg[4][16][49];           // per-wave logits
    __shared__ float blin_s[48];

    const int tid  = threadIdx.x;
    const int row0 = blockIdx.x * 64;

    for (int i = tid; i < 48 * 200; i += 256) wt[i] = 0;
    if (tid < 48) blin_s[tid] = (tid < 40) ? blin[tid] : 0.f;
    __syncthreads();  // zeros visible before sparse overwrite below
    for (int i = tid; i < 192 * 40; i += 256) {
        int k = i / 40, n = i % 40;
        wt[n * 200 + k] = f2b(Wlin[i]);
    }
    for (int i = tid; i < 64 * 64; i += 256) {
        int r = i >> 6, c = i & 63;
        int grow = row0 + r;
        bool ok = grow < Nn;
        xs[r * 200 + c]       = ok ? f2b(x1[grow * 64 + c]) : 0;
        xs[r * 200 + 64 + c]  = ok ? f2b(x2[grow * 64 + c]) : 0;
        xs[r * 200 + 128 + c] = ok ? f2b(x3[grow * 64 + c]) : 0;
    }
    __syncthreads();

    const int wv   = tid >> 6;
    const int lane = tid & 63;
    const int l15  = lane & 15;
    const int quad = lane >> 4;

    short8 a[6];
    const unsigned short* arow = xs + (wv * 16 + l15) * 200 + quad * 8;
#pragma unroll
    for (int ks = 0; ks < 6; ++ks) a[ks] = *(const short8*)(arow + ks * 32);

#pragma unroll
    for (int nt = 0; nt < 3; ++nt) {
        f32x4 acc = {0.f, 0.f, 0.f, 0.f};
        const unsigned short* brow = wt + (nt * 16 + l15) * 200 + quad * 8;
#pragma unroll
        for (int ks = 0; ks < 6; ++ks) {
            short8 b = *(const short8*)(brow + ks * 32);
            acc = __builtin_amdgcn_mfma_f32_16x16x32_bf16(a[ks], b, acc, 0, 0, 0);
        }
#pragma unroll
        for (int reg = 0; reg < 4; ++reg)
            lg[wv][quad * 4 + reg][nt * 16 + l15] = acc[reg];
    }
    // intra-wave LDS write->read: compiler inserts lgkmcnt wait; no barrier.

    // log_softmax: 4 lanes per row, 10 classes each
    const int r    = l15;
    const int part = quad;           // class chunk part*10 .. part*10+9
    float v[10];
    float mx = -INFINITY;
#pragma unroll
    for (int j = 0; j < 10; ++j) {
        v[j] = lg[wv][r][part * 10 + j] + blin_s[part * 10 + j];
        mx = fmaxf(mx, v[j]);
    }
    mx = fmaxf(mx, __shfl_xor(mx, 16));
    mx = fmaxf(mx, __shfl_xor(mx, 32));
    float s = 0.f;
#pragma unroll
    for (int j = 0; j < 10; ++j) s += expf(v[j] - mx);
    s += __shfl_xor(s, 16);
    s += __shfl_xor(s, 32);
    float lse = mx + logf(s);
    int grow = row0 + wv * 16 + r;
    if (grow < Nn) {
#pragma unroll
        for (int j = 0; j < 10; ++j)
            out[grow * NCLS + part * 10 + j] = v[j] - lse;
    }
}

// ---------------------------------------------------------------------------
extern "C" void kernel_launch(void* const* d_in, const int* in_sizes, int n_in,
                              void* d_out, int out_size, void* d_ws, size_t ws_size,
                              hipStream_t stream) {
    const float* x0  = (const float*)d_in[0];
    const int*   ei  = (const int*)d_in[1];
    const float* ew  = (const float*)d_in[2];
    const float* W1l = (const float*)d_in[3];
    const float* W1r = (const float*)d_in[4];
    const float* b1  = (const float*)d_in[5];
    const float* W2l = (const float*)d_in[6];
    const float* W2r = (const float*)d_in[7];
    const float* b2  = (const float*)d_in[8];
    const float* W3l = (const float*)d_in[9];
    const float* W3r = (const float*)d_in[10];
    const float* b3  = (const float*)d_in[11];
    const float* Wlin = (const float*)d_in[12];
    const float* blin = (const float*)d_in[13];
    float* out = (float*)d_out;

    const int* src = ei;       // edge_index[0]
    const int* dst = ei + Ee;  // edge_index[1]

    // Workspace layout (4-byte elements; edgeA 8-byte aligned by construction)
    const size_t N64 = (size_t)Nn * 64;
    char* ws = (char*)d_ws;
    int*   cnt    = (int*)ws;                       // 50048
    int*   rowptr = cnt + 50048;                    // 50048 (Nn+1 used)
    int*   cursor = rowptr + 50048;                 // 50048
    int*   bsum   = cursor + 50048;                 // 256 (196 used)
    int2*  edgeA  = (int2*)(bsum + 256);            // Ee (8B each)
    float* yl     = (float*)(edgeA + Ee);           // N64
    float* zb     = yl + N64;                       // N64
    float* x1     = zb + N64;                       // N64
    float* x2     = x1 + N64;                       // N64
    float* x3     = x2 + N64;                       // N64

    const int eblocks     = (Ee + 255) / 256;
    const int gemm_blocks = Nn / 16;       // exact
    const int row_blocks  = Nn / 4;        // gather: 4 rows/block, exact
    const int fin_blocks  = (Nn + 63) / 64;

    // ---- CSR build (per call; ws is re-poisoned) ----
    hipMemsetAsync(cnt, 0, Nn * sizeof(int), stream);
    count_kernel<<<eblocks, 256, 0, stream>>>(dst, cnt);
    scanA_kernel<<<SCAN_BLOCKS, 256, 0, stream>>>(cnt, rowptr, bsum);
    scanC_kernel<<<SCAN_BLOCKS, 256, 0, stream>>>(rowptr, bsum, cursor);
    fill_kernel<<<NPART * SLICES, 256, 0, stream>>>(src, dst, ew, cursor, edgeA);

    // ---- layer 1 (K = 128) ----
    gemm2_kernel<FIN><<<gemm_blocks, 256, 0, stream>>>(x0, W1l, W1r, b1, yl, zb);
    gather_kernel<<<row_blocks, 256, 0, stream>>>(rowptr, edgeA, yl, zb, x1);

    // ---- layer 2 (K = 64) ----
    gemm2_kernel<HID><<<gemm_blocks, 256, 0, stream>>>(x1, W2l, W2r, b2, yl, zb);
    gather_kernel<<<row_blocks, 256, 0, stream>>>(rowptr, edgeA, yl, zb, x2);

    // ---- layer 3 (K = 64) ----
    gemm2_kernel<HID><<<gemm_blocks, 256, 0, stream>>>(x2, W3l, W3r, b3, yl, zb);
    gather_kernel<<<row_blocks, 256, 0, stream>>>(rowptr, edgeA, yl, zb, x3);

    // ---- final linear + log_softmax (bf16 MFMA) ----
    final_kernel<<<fin_blocks, 256, 0, stream>>>(x1, x2, x3, Wlin, blin, out);
}